// Round 7
// baseline (13458.064 us; speedup 1.0000x reference)
//
#include <hip/hip_runtime.h>
#include <cmath>

#define HID   512
#define VOCAB 100
#define G3    1536            // 3*HID
#define GEXT  1664            // G3 + 100 logits + 28 pad (104 tiles of 16)
#define NT    104             // column tiles of 16
#define TMAX  201
#define ROWS  16
#define BLOCK 1024            // 16 waves
#define NWAVE 16
#define NWG   128

typedef __bf16 bf16x8 __attribute__((ext_vector_type(8)));
typedef float  f32x4  __attribute__((ext_vector_type(4)));

// ---- workspace layout ----
// WPK (bf16): packed MFMA B-fragments, [tile][kstep][half(hi/lo)][lane][8]
#define SZ_WPK   (NT * 16 * 2 * 64 * 8)   // 1,703,936 bf16 = 3.4 MB
#define FBASE    (SZ_WPK / 2)             // float-index base after WPK
#define OFF_EIH  FBASE                    // E_ih = embed @ W_ih^T + b_ih   [100][1536] f32
#define SZ_EIH   (VOCAB * G3)
#define OFF_WIHT (OFF_EIH + SZ_EIH)       // W_ih transposed [k][j] f32
#define SZ_WIHT  (HID * G3)
#define OFF_BEXT (OFF_WIHT + SZ_WIHT)     // [b_hh | b_proj | 0-pad]  [1664] f32

// Build W_ihT and bias_ext.
__global__ void prep_kernel(const float* __restrict__ W_ih,
                            const float* __restrict__ b_hh,
                            const float* __restrict__ b_proj,
                            float* __restrict__ ws)
{
  int idx = blockIdx.x * 256 + threadIdx.x;
  if (idx < SZ_WIHT) {
    int k = idx / G3, j = idx - k * G3;
    ws[OFF_WIHT + idx] = W_ih[j * HID + k];
  } else if (idx < SZ_WIHT + GEXT) {
    int j = idx - SZ_WIHT;
    float v = 0.f;
    if (j < G3)              v = b_hh[j];
    else if (j < G3 + VOCAB) v = b_proj[j - G3];
    ws[OFF_BEXT + j] = v;
  }
}

// Pack W (= [W_hh rows | W_proj rows | 0]) into split-bf16 MFMA B-fragments.
// B-frag layout for mfma_f32_16x16x32_bf16: lane l holds B[k=(l>>4)*8+j][col=l&15].
__global__ void pack_kernel(const float* __restrict__ W_hh,
                            const float* __restrict__ W_proj,
                            __bf16* __restrict__ wpk)
{
  int idx = blockIdx.x * 256 + threadIdx.x;      // element (c,ks,lane,j)
  if (idx >= NT * 16 * 64 * 8) return;
  int j    = idx & 7;
  int lane = (idx >> 3) & 63;
  int ks   = (idx >> 9) & 15;
  int c    = idx >> 13;
  int col  = c * 16 + (lane & 15);
  int k    = ks * 32 + (lane >> 4) * 8 + j;
  float w = 0.f;
  if (col < G3)              w = W_hh[col * HID + k];
  else if (col < G3 + VOCAB) w = W_proj[(col - G3) * HID + k];
  __bf16 hi = (__bf16)w;
  __bf16 lo = (__bf16)(w - (float)hi);
  int base = (((c * 16 + ks) * 2) * 64 + lane) * 8 + j;
  wpk[base]       = hi;
  wpk[base + 512] = lo;                          // lo-half is +64*8 elements
}

// E_ih[v][j] = b_ih[j] + sum_k embed[v][k] * W_ih[j][k]
__global__ void eih_kernel(const float* __restrict__ embed,
                           const float* __restrict__ b_ih,
                           float* __restrict__ ws)
{
  int v = blockIdx.x / 6;
  int j = (blockIdx.x % 6) * 256 + threadIdx.x;
  const float* WihT = ws + OFF_WIHT;
  const float* e = embed + v * HID;
  float acc = b_ih[j];
  for (int k = 0; k < HID; ++k)
    acc = fmaf(WihT[k * G3 + j], e[k], acc);
  ws[OFF_EIH + v * G3 + j] = acc;
}

// Persistent GRU decode, 16 rows/block, 16 waves, MFMA split-bf16.
// A_hi = H_hi (16 rows), A_lo = H_lo (16 rows); all 4 cross-terms accumulate
// into one 16-row acc = exact (H_hi+H_lo)@(W_hi+W_lo). No shuffle combine.
__global__ __launch_bounds__(BLOCK) void decode_kernel(
    const float* __restrict__ feat,
    const int* __restrict__ sos,
    const float* __restrict__ ws,
    const __bf16* __restrict__ wpk,
    float* __restrict__ out)
{
  __shared__ __align__(16) char hab[32 * 1024];   // rows 0-15 = hi, 16-31 = lo; XOR-swizzled
  __shared__ float gh[ROWS][GEXT + 1];            // 106.6 KB; stride 1665 spreads banks
  __shared__ int   pred_lds[ROWS];

  const float* __restrict__ EIH  = ws + OFF_EIH;
  const float* __restrict__ bext = ws + OFF_BEXT;

  const int tid  = threadIdx.x;
  const int lane = tid & 63;
  const int wv   = tid >> 6;          // wave 0..15
  const int b0   = blockIdx.x * ROWS;
  const int u    = tid & (HID - 1);   // unit 0..511
  const int rb   = (tid >> 9) * 8;    // row base 0 or 8

  // ---- init: h in regs (8 rows per thread), split-bf16 into hab ----
  float h[8];
  #pragma unroll
  for (int r8 = 0; r8 < 8; ++r8) {
    int r = rb + r8;
    float f = feat[(size_t)(b0 + r) * HID + u];
    h[r8] = f;
    __bf16 hi = (__bf16)f;
    __bf16 lo = (__bf16)(f - (float)hi);
    unsigned so = ((unsigned)(u * 2)) ^ (((unsigned)(r & 7)) << 4);
    *(__bf16*)(hab + (r << 10) + so)        = hi;
    *(__bf16*)(hab + ((r + 16) << 10) + so) = lo;
  }
  if (tid < ROWS) pred_lds[tid] = sos[0];
  __syncthreads();

  // A-frag addressing: lane l reads A[row=l&15][k=(l>>4)*8+j]
  const int      arow = lane & 15;
  const unsigned ag   = (unsigned)((lane >> 4) << 4);
  const unsigned axor = ((unsigned)(arow & 7)) << 4;
  const char* ha_hi = hab + (arow << 10);
  const char* ha_lo = ha_hi + (16 << 10);

  for (int t = 0; t <= TMAX; ++t) {
    // ---------- phase A: MFMA over this wave's tiles ----------
    for (int tile = wv; tile < NT; tile += NWAVE) {
      if (t == TMAX && tile < 96) continue;     // last iter: logits only
      f32x4 acc = {0.f, 0.f, 0.f, 0.f};
      const bf16x8* bp = ((const bf16x8*)wpk) + (size_t)tile * 2048 + lane;
      #pragma unroll 4
      for (int ks = 0; ks < 16; ++ks) {
        unsigned aoff = (((unsigned)ks << 6) + ag) ^ axor;
        bf16x8 ahi = *(const bf16x8*)(ha_hi + aoff);
        bf16x8 alo = *(const bf16x8*)(ha_lo + aoff);
        bf16x8 bhi = __builtin_nontemporal_load(bp + ks * 128);
        bf16x8 blo = __builtin_nontemporal_load(bp + ks * 128 + 64);
        acc = __builtin_amdgcn_mfma_f32_16x16x32_bf16(ahi, bhi, acc, 0, 0, 0);
        acc = __builtin_amdgcn_mfma_f32_16x16x32_bf16(alo, bhi, acc, 0, 0, 0);
        acc = __builtin_amdgcn_mfma_f32_16x16x32_bf16(ahi, blo, acc, 0, 0, 0);
        acc = __builtin_amdgcn_mfma_f32_16x16x32_bf16(alo, blo, acc, 0, 0, 0);
      }
      int colw = tile * 16 + (lane & 15);
      float bias = bext[colw];
      int r0 = (lane >> 4) * 4;
      #pragma unroll
      for (int i = 0; i < 4; ++i)
        gh[r0 + i][colw] = acc[i] + bias;
    }
    __syncthreads();   // gh (gates + logits) ready

    // ---------- logits out + wave-parallel argmax ----------
    if (t >= 1) {
      // ROWS*VOCAB = 1600 > BLOCK: strided loop (round-5 bug: single-shot
      // `if (tid < 1600)` left rows 10-15 unwritten)
      for (int i = tid; i < ROWS * VOCAB; i += BLOCK) {
        int r = i / VOCAB, v = i - r * VOCAB;
        __builtin_nontemporal_store(
            gh[r][G3 + v],
            &out[((size_t)(b0 + r) * VOCAB + v) * TMAX + (t - 1)]);
      }
      if (t < TMAX) {            // wave wv reduces row wv (first-max semantics)
        float v0 = (lane < VOCAB)      ? gh[wv][G3 + lane]      : -1e30f;
        float v1 = (lane + 64 < VOCAB) ? gh[wv][G3 + 64 + lane] : -1e30f;
        float bv; int bi;
        if (v0 >= v1) { bv = v0; bi = lane; } else { bv = v1; bi = lane + 64; }
        #pragma unroll
        for (int off = 32; off >= 1; off >>= 1) {
          float ov = __shfl_xor(bv, off);
          int   oi = __shfl_xor(bi, off);
          if (ov > bv || (ov == bv && oi < bi)) { bv = ov; bi = oi; }
        }
        if (lane == 0) pred_lds[wv] = bi;
      }
    }
    __syncthreads();   // pred ready

    // ---------- gate nonlinearity + h update + split-bf16 writeback ----------
    if (t < TMAX) {
      #pragma unroll
      for (int r8 = 0; r8 < 8; ++r8) {
        int r = rb + r8;
        const float* eb = EIH + (size_t)pred_lds[r] * G3;
        float rg = 1.f / (1.f + expf(-(eb[u]           + gh[r][u])));
        float zg = 1.f / (1.f + expf(-(eb[HID + u]     + gh[r][HID + u])));
        float ng = tanhf(eb[2 * HID + u] + rg * gh[r][2 * HID + u]);
        h[r8] = (1.f - zg) * ng + zg * h[r8];
        __bf16 hi = (__bf16)h[r8];
        __bf16 lo = (__bf16)(h[r8] - (float)hi);
        unsigned so = ((unsigned)(u * 2)) ^ (((unsigned)(r & 7)) << 4);
        *(__bf16*)(hab + (r << 10) + so)        = hi;
        *(__bf16*)(hab + ((r + 16) << 10) + so) = lo;
      }
    }
    __syncthreads();   // hab ready for next step; gh free to overwrite
  }
}

extern "C" void kernel_launch(void* const* d_in, const int* in_sizes, int n_in,
                              void* d_out, int out_size, void* d_ws, size_t ws_size,
                              hipStream_t stream)
{
  const float* feat   = (const float*)d_in[0];
  const float* W_ih   = (const float*)d_in[1];
  const float* W_hh   = (const float*)d_in[2];
  const float* b_ih   = (const float*)d_in[3];
  const float* b_hh   = (const float*)d_in[4];
  const float* W_proj = (const float*)d_in[5];
  const float* b_proj = (const float*)d_in[6];
  const float* embed  = (const float*)d_in[7];
  const int*   sos    = (const int*)d_in[8];

  float*  wsf = (float*)d_ws;
  __bf16* wpk = (__bf16*)d_ws;
  float*  out = (float*)d_out;

  const int prep_total = SZ_WIHT + GEXT;
  prep_kernel<<<(prep_total + 255) / 256, 256, 0, stream>>>(W_ih, b_hh, b_proj, wsf);
  pack_kernel<<<(NT * 16 * 64 * 8 + 255) / 256, 256, 0, stream>>>(W_hh, W_proj, wpk);
  eih_kernel<<<600, 256, 0, stream>>>(embed, b_ih, wsf);
  decode_kernel<<<NWG, BLOCK, 0, stream>>>(feat, sos, wsf, wpk, out);
}

// Round 8
// 6630.630 us; speedup vs baseline: 2.0297x; 2.0297x over previous
//
#include <hip/hip_runtime.h>
#include <cmath>

#define HID   512
#define VOCAB 100
#define G3    1536            // 3*HID
#define GEXT  1664            // G3 + 100 logits + 28 pad (104 tiles of 16)
#define NT    104             // column tiles of 16
#define TMAX  201
#define ROWS  8
#define BLOCK 1024            // 16 waves: 8 tile-sets x 2 k-halves
#define NWG   256
#define TPW   13              // tiles per tile-set (104/8)
#define GHS   1672            // gh row stride (floats), ==8 mod 32 -> 2-way-free writes

typedef __bf16 bf16x8 __attribute__((ext_vector_type(8)));
typedef float  f32x4  __attribute__((ext_vector_type(4)));

// ---- workspace layout ----
// WPK (bf16): packed MFMA B-fragments, [tile][kstep][half(hi/lo)][lane][8]
#define SZ_WPK   (NT * 16 * 2 * 64 * 8)   // 1,703,936 bf16 = 3.4 MB
#define FBASE    (SZ_WPK / 2)             // float-index base after WPK
#define OFF_EIH  FBASE                    // E_ih = embed @ W_ih^T + b_ih   [100][1536] f32
#define SZ_EIH   (VOCAB * G3)
#define OFF_WIHT (OFF_EIH + SZ_EIH)       // W_ih transposed [k][j] f32
#define SZ_WIHT  (HID * G3)
#define OFF_BEXT (OFF_WIHT + SZ_WIHT)     // [b_hh | b_proj | 0-pad]  [1664] f32

// Build W_ihT and bias_ext.
__global__ void prep_kernel(const float* __restrict__ W_ih,
                            const float* __restrict__ b_hh,
                            const float* __restrict__ b_proj,
                            float* __restrict__ ws)
{
  int idx = blockIdx.x * 256 + threadIdx.x;
  if (idx < SZ_WIHT) {
    int k = idx / G3, j = idx - k * G3;
    ws[OFF_WIHT + idx] = W_ih[j * HID + k];
  } else if (idx < SZ_WIHT + GEXT) {
    int j = idx - SZ_WIHT;
    float v = 0.f;
    if (j < G3)              v = b_hh[j];
    else if (j < G3 + VOCAB) v = b_proj[j - G3];
    ws[OFF_BEXT + j] = v;
  }
}

// Pack W (= [W_hh rows | W_proj rows | 0]) into split-bf16 MFMA B-fragments.
// B-frag layout for mfma_f32_16x16x32_bf16: lane l holds B[k=(l>>4)*8+j][col=l&15].
__global__ void pack_kernel(const float* __restrict__ W_hh,
                            const float* __restrict__ W_proj,
                            __bf16* __restrict__ wpk)
{
  int idx = blockIdx.x * 256 + threadIdx.x;      // element (c,ks,lane,j)
  if (idx >= NT * 16 * 64 * 8) return;
  int j    = idx & 7;
  int lane = (idx >> 3) & 63;
  int ks   = (idx >> 9) & 15;
  int c    = idx >> 13;
  int col  = c * 16 + (lane & 15);
  int k    = ks * 32 + (lane >> 4) * 8 + j;
  float w = 0.f;
  if (col < G3)              w = W_hh[col * HID + k];
  else if (col < G3 + VOCAB) w = W_proj[(col - G3) * HID + k];
  __bf16 hi = (__bf16)w;
  __bf16 lo = (__bf16)(w - (float)hi);
  int base = (((c * 16 + ks) * 2) * 64 + lane) * 8 + j;
  wpk[base]       = hi;
  wpk[base + 512] = lo;                          // lo-half is +64*8 elements
}

// E_ih[v][j] = b_ih[j] + sum_k embed[v][k] * W_ih[j][k]
__global__ void eih_kernel(const float* __restrict__ embed,
                           const float* __restrict__ b_ih,
                           float* __restrict__ ws)
{
  int v = blockIdx.x / 6;
  int j = (blockIdx.x % 6) * 256 + threadIdx.x;
  const float* WihT = ws + OFF_WIHT;
  const float* e = embed + v * HID;
  float acc = b_ih[j];
  for (int k = 0; k < HID; ++k)
    acc = fmaf(WihT[k * G3 + j], e[k], acc);
  ws[OFF_EIH + v * G3 + j] = acc;
}

// Persistent GRU decode: 8 rows/block, 256 blocks (all CUs), 16 waves.
// Waves wt and wt+8 cover the same 13 tiles, splitting k (ks 0-7 / 8-15),
// writing partial sums to ghA / ghB; consumers compute ghA+ghB+bias in a
// fixed order (deterministic). A tile = [H_hi(8); H_lo(8)], B passes hi+lo:
// acc rows r + r+8 combined by shfl_xor(32) = exact fp32-accurate H @ W.
__global__ __launch_bounds__(BLOCK) void decode_kernel(
    const float* __restrict__ feat,
    const int* __restrict__ sos,
    const float* __restrict__ ws,
    const __bf16* __restrict__ wpk,
    float* __restrict__ out)
{
  __shared__ __align__(16) char hab[16 * 1024];   // rows 0-7 hi, 8-15 lo; XOR-swizzled
  __shared__ float ghA[ROWS][GHS];                // k-half 0 partials (53.5 KB)
  __shared__ float ghB[ROWS][GHS];                // k-half 1 partials
  __shared__ int   pred_lds[ROWS];

  const float* __restrict__ EIH  = ws + OFF_EIH;
  const float* __restrict__ bext = ws + OFF_BEXT;

  const int tid  = threadIdx.x;
  const int lane = tid & 63;
  const int wv   = tid >> 6;          // wave 0..15
  const int half = wv >> 3;           // k-half 0/1
  const int wt   = wv & 7;            // tile-set 0..7
  const int b0   = blockIdx.x * ROWS;
  const int u    = tid & (HID - 1);   // unit 0..511
  const int rb   = (tid >> 9) * 4;    // row base 0 or 4 (4 rows per thread)

  float (*ghW)[GHS] = half ? ghB : ghA;

  // ---- init: h in regs (4 rows per thread), split-bf16 into hab ----
  float h[4];
  #pragma unroll
  for (int rr = 0; rr < 4; ++rr) {
    int r = rb + rr;
    float f = feat[(size_t)(b0 + r) * HID + u];
    h[rr] = f;
    __bf16 hi = (__bf16)f;
    __bf16 lo = (__bf16)(f - (float)hi);
    unsigned so = ((unsigned)(u * 2)) ^ (((unsigned)(r & 7)) << 4);
    *(__bf16*)(hab + (r << 10) + so)       = hi;
    *(__bf16*)(hab + ((r + 8) << 10) + so) = lo;
  }
  if (tid < ROWS) pred_lds[tid] = sos[0];
  __syncthreads();

  // per-thread consumer biases (b_hh gates; b_proj for store/argmax)
  const float gbr = bext[u], gbz = bext[HID + u], gbn = bext[2 * HID + u];
  const int sr = tid / VOCAB, sv = tid - sr * VOCAB;       // store role (tid<800)
  float* outp = nullptr; float outb = 0.f;
  if (tid < ROWS * VOCAB) {
    outp = out + ((size_t)(b0 + sr) * VOCAB + sv) * TMAX;
    outb = bext[G3 + sv];
  }
  const float ab0 = (lane < VOCAB)      ? bext[G3 + lane]      : 0.f;
  const float ab1 = (lane + 64 < VOCAB) ? bext[G3 + 64 + lane] : 0.f;

  // A-frag addressing: lane l reads A[row=l&15][k=(l>>4)*8+j]
  const int      arow = lane & 15;
  const unsigned ag   = (unsigned)((lane >> 4) << 4);
  const unsigned axor = ((unsigned)(arow & 7)) << 4;
  const char* ha = hab + (arow << 10);

  for (int t = 0; t <= TMAX; ++t) {
    // ---------- A-frags for this wave's k-half (reused across 13 tiles) ----------
    bf16x8 afr[8];
    #pragma unroll
    for (int q = 0; q < 8; ++q) {
      int ks = half * 8 + q;
      afr[q] = *(const bf16x8*)(ha + ((((unsigned)ks << 6) + ag) ^ axor));
    }

    // ---------- phase A: MFMA over this wave's tiles, k-half only ----------
    for (int tt = 0; tt < TPW; ++tt) {
      int tile = wt * TPW + tt;
      if (t == TMAX && tile < 96) continue;     // last iter: logits only
      f32x4 acc = {0.f, 0.f, 0.f, 0.f};
      const bf16x8* bp = ((const bf16x8*)wpk)
                         + (size_t)tile * 2048 + (size_t)half * 1024 + lane;
      #pragma unroll
      for (int q = 0; q < 8; ++q) {
        bf16x8 bh = bp[q * 128];
        bf16x8 bl = bp[q * 128 + 64];
        acc = __builtin_amdgcn_mfma_f32_16x16x32_bf16(afr[q], bh, acc, 0, 0, 0);
        acc = __builtin_amdgcn_mfma_f32_16x16x32_bf16(afr[q], bl, acc, 0, 0, 0);
      }
      // rows 8-15 (lanes 32-63) hold the H_lo terms; fold into rows 0-7
      int colw = tile * 16 + (lane & 15);
      float vs[4];
      #pragma unroll
      for (int i = 0; i < 4; ++i)
        vs[i] = acc[i] + __shfl_xor(acc[i], 32, 64);
      if (lane < 32) {
        int r0 = (lane >> 4) * 4;
        #pragma unroll
        for (int i = 0; i < 4; ++i)
          ghW[r0 + i][colw] = vs[i];
      }
    }
    __syncthreads();   // ghA+ghB (gates + logits) ready

    // ---------- logits out + wave-parallel argmax ----------
    if (t >= 1) {
      if (tid < ROWS * VOCAB) {   // 800 <= 1024: full coverage, single shot
        float lg = ghA[sr][G3 + sv] + ghB[sr][G3 + sv] + outb;
        __builtin_nontemporal_store(lg, outp + (t - 1));
      }
      if (t < TMAX && wv < ROWS) {   // wave wv reduces row wv (first-max semantics)
        float v0 = (lane < VOCAB)
                   ? ghA[wv][G3 + lane] + ghB[wv][G3 + lane] + ab0 : -1e30f;
        float v1 = (lane + 64 < VOCAB)
                   ? ghA[wv][G3 + 64 + lane] + ghB[wv][G3 + 64 + lane] + ab1 : -1e30f;
        float bv; int bi;
        if (v0 >= v1) { bv = v0; bi = lane; } else { bv = v1; bi = lane + 64; }
        #pragma unroll
        for (int off = 32; off >= 1; off >>= 1) {
          float ov = __shfl_xor(bv, off);
          int   oi = __shfl_xor(bi, off);
          if (ov > bv || (ov == bv && oi < bi)) { bv = ov; bi = oi; }
        }
        if (lane == 0) pred_lds[wv] = bi;
      }
    }
    __syncthreads();   // pred ready

    // ---------- gate nonlinearity + h update + split-bf16 writeback ----------
    if (t < TMAX) {
      #pragma unroll
      for (int rr = 0; rr < 4; ++rr) {
        int r = rb + rr;
        const float* eb = EIH + (size_t)pred_lds[r] * G3;
        float srg = eb[u]       + gbr + ghA[r][u]       + ghB[r][u];
        float szg = eb[HID + u] + gbz + ghA[r][HID + u] + ghB[r][HID + u];
        float hn  = ghA[r][2 * HID + u] + ghB[r][2 * HID + u] + gbn; // b_hh_n inside r*(...)
        float rg = 1.f / (1.f + expf(-srg));
        float zg = 1.f / (1.f + expf(-szg));
        float ng = tanhf(eb[2 * HID + u] + rg * hn);
        h[rr] = (1.f - zg) * ng + zg * h[rr];
        __bf16 hi = (__bf16)h[rr];
        __bf16 lo = (__bf16)(h[rr] - (float)hi);
        unsigned so = ((unsigned)(u * 2)) ^ (((unsigned)(r & 7)) << 4);
        *(__bf16*)(hab + (r << 10) + so)       = hi;
        *(__bf16*)(hab + ((r + 8) << 10) + so) = lo;
      }
    }
    __syncthreads();   // hab ready for next step; gh free to overwrite
  }
}

extern "C" void kernel_launch(void* const* d_in, const int* in_sizes, int n_in,
                              void* d_out, int out_size, void* d_ws, size_t ws_size,
                              hipStream_t stream)
{
  const float* feat   = (const float*)d_in[0];
  const float* W_ih   = (const float*)d_in[1];
  const float* W_hh   = (const float*)d_in[2];
  const float* b_ih   = (const float*)d_in[3];
  const float* b_hh   = (const float*)d_in[4];
  const float* W_proj = (const float*)d_in[5];
  const float* b_proj = (const float*)d_in[6];
  const float* embed  = (const float*)d_in[7];
  const int*   sos    = (const int*)d_in[8];

  float*  wsf = (float*)d_ws;
  __bf16* wpk = (__bf16*)d_ws;
  float*  out = (float*)d_out;

  const int prep_total = SZ_WIHT + GEXT;
  prep_kernel<<<(prep_total + 255) / 256, 256, 0, stream>>>(W_ih, b_hh, b_proj, wsf);
  pack_kernel<<<(NT * 16 * 64 * 8 + 255) / 256, 256, 0, stream>>>(W_hh, W_proj, wpk);
  eih_kernel<<<600, 256, 0, stream>>>(embed, b_ih, wsf);
  decode_kernel<<<NWG, BLOCK, 0, stream>>>(feat, sos, wsf, wpk, out);
}